// Round 8
// baseline (33.962 us; speedup 1.0000x reference)
//
#include <hip/hip_runtime.h>
#include <utility>
#include <cmath>

// Problem constants (fixed by the reference setup)
constexpr int T = 2048;
constexpr int B = 8;
constexpr int C = 1024;
constexpr int H = 16;
constexpr int K = 31;
constexpr int PAD = 15;            // PADDING_L
constexpr int NBC = B * C;         // 8192 = t-stride in elements; (b,c) contiguous
constexpr int BLOCK = 256;         // 4 waves; each wave spans 64 bc -> one head
constexpr int TT = 32;             // t-outputs per tile
constexpr int WIN = TT + K - 1;    // 62-row register window (statically indexed)
constexpr int TILES = 4;           // t-tiles per block, sliding window between them

// One tap: KK compile-time -> w[KK] stays in SGPR, xv[i+KK] statically-indexed reg.
template <int KK>
__device__ __forceinline__ void tap(float (&acc)[TT], const float (&xv)[WIN], float wk) {
#pragma unroll
    for (int i = 0; i < TT; ++i)
        acc[i] = fmaf(wk, xv[i + KK], acc[i]);
}

template <int... Ks>
__device__ __forceinline__ void all_taps(float (&acc)[TT], const float (&xv)[WIN],
                                         const float (&w)[K],
                                         std::integer_sequence<int, Ks...>) {
    (tap<Ks>(acc, xv, w[Ks]), ...);
}

// Broadcast tap k from lane k to all lanes as wave-uniform (SGPR) values,
// with compile-time lane indices (v_readlane_b32 with literal lane).
template <int... Ks>
__device__ __forceinline__ void bcast_taps(float (&w)[K], float v,
                                           std::integer_sequence<int, Ks...>) {
    ((w[Ks] = __int_as_float(__builtin_amdgcn_readlane(__float_as_int(v), Ks))), ...);
}

__global__ __launch_bounds__(BLOCK, 3) void lconv_tbc_kernel(
    const float* __restrict__ x,      // (T, B, C)
    const float* __restrict__ wgt,    // (H, 1, K)
    const float* __restrict__ bias,   // (C)
    float* __restrict__ out)          // (T, B, C)
{
    const int tid  = threadIdx.x;
    const int lane = tid & 63;
    const int bc   = blockIdx.x * BLOCK + tid;   // contiguous per wave
    const int c    = bc & (C - 1);
    const int t0   = blockIdx.y * (TILES * TT);  // 128-row strip per block

    // ---- per-wave softmax of this wave's head (64 bc columns == one head) ----
    const int head = c >> 6;                     // wave-uniform
    float raw = (lane < K) ? wgt[head * K + lane] : -INFINITY;
    float m = raw;
    #pragma unroll
    for (int off = 32; off >= 1; off >>= 1) m = fmaxf(m, __shfl_xor(m, off));
    float e = (lane < K) ? expf(raw - m) : 0.0f;
    float s = e;
    #pragma unroll
    for (int off = 32; off >= 1; off >>= 1) s += __shfl_xor(s, off);
    const float myw = e / s;                     // lanes >= K hold 0

    float w[K];
    bcast_taps(w, myw, std::make_integer_sequence<int, K>{});   // 31x v_readlane -> SGPRs
    const float bb = bias[c];

    // ---- initial 62-row window: rows t0-15 .. t0+46 (branchless edge mask) ----
    float xv[WIN];
    #pragma unroll
    for (int j = 0; j < WIN; ++j) {
        const int tg = t0 - PAD + j;
        xv[j] = ((unsigned)tg < (unsigned)T)
                  ? x[(ptrdiff_t)tg * NBC + bc] : 0.0f;
    }

    // ---- 4 tiles, sliding the window by TT rows each time ----
    float xn[TT];
    #pragma unroll 1
    for (int it = 0; it < TILES; ++it) {
        // prefetch next tile's 32 new rows (t0+47+32*it ..) before computing;
        // their latency hides under the 992 FMAs below
        if (it + 1 < TILES) {
            const int tn0 = t0 + (WIN - PAD) + it * TT;   // first new row
            #pragma unroll
            for (int j = 0; j < TT; ++j) {
                const int tg = tn0 + j;
                xn[j] = (tg < T) ? x[(ptrdiff_t)tg * NBC + bc] : 0.0f;
            }
        }
        __builtin_amdgcn_sched_barrier(0);   // don't sink prefetch below the FMAs

        float acc[TT];
        #pragma unroll
        for (int i = 0; i < TT; ++i) acc[i] = 0.0f;
        all_taps(acc, xv, w, std::make_integer_sequence<int, K>{});   // 31x32 static FMAs

        float* op = out + (size_t)(t0 + it * TT) * NBC + bc;
        #pragma unroll
        for (int i = 0; i < TT; ++i)
            __builtin_nontemporal_store(acc[i] + bb, &op[(size_t)i * NBC]);

        // slide window: keep last K-1 rows, append the 32 prefetched rows
        if (it + 1 < TILES) {
            #pragma unroll
            for (int j = 0; j < WIN - TT; ++j) xv[j] = xv[j + TT];
            #pragma unroll
            for (int j = 0; j < TT; ++j)       xv[WIN - TT + j] = xn[j];
        }
    }
}

extern "C" void kernel_launch(void* const* d_in, const int* in_sizes, int n_in,
                              void* d_out, int out_size, void* d_ws, size_t ws_size,
                              hipStream_t stream) {
    const float* x    = (const float*)d_in[0];
    const float* wgt  = (const float*)d_in[1];
    const float* bias = (const float*)d_in[2];
    float* out        = (float*)d_out;

    dim3 grid(NBC / BLOCK, T / (TILES * TT));   // (32, 16) = 512 blocks, no barriers
    lconv_tbc_kernel<<<grid, dim3(BLOCK), 0, stream>>>(x, wgt, bias, out);
}